// Round 5
// baseline (179.931 us; speedup 1.0000x reference)
//
#include <hip/hip_runtime.h>
#include <hip/hip_bf16.h>

// VectorQuantizerEMA: N=16384, K=1024, D=256.
// Outputs (f32, concat): recons [N,D] | gamma [N,K] | new_centroids [K,D]
// R5: 5 kernels (was 9). prep fuses cent hi/lo + csq + ws-zero + sum(ema_cs);
// wave-per-row softmax (no barriers); finalize computes newcs inline using
// n = 0.95*sum(ema_cs) + 0.05*N (since sum(counts) == N exactly).

#define DECAY 0.95f
#define OMD   0.05f
#define EPSV  1e-5f

using f32x4  = __attribute__((ext_vector_type(4))) float;
using bf16x8 = __attribute__((ext_vector_type(8))) __bf16;

typedef __attribute__((address_space(3))) unsigned int       lds_uint;
typedef const __attribute__((address_space(1))) unsigned int glb_uint;

__device__ __forceinline__ void gload16(const void* g, const void* l) {
  __builtin_amdgcn_global_load_lds((glb_uint*)(unsigned long long)g,
                                   (lds_uint*)(unsigned int)(unsigned long long)l,
                                   16, 0, 0);
}

__device__ __forceinline__ unsigned short f2bf(float f) {
  unsigned int u = __float_as_uint(f);
  unsigned int r = (u + 0x7FFFu + ((u >> 16) & 1u)) >> 16;
  return (unsigned short)r;
}
__device__ __forceinline__ float bf2f(unsigned short s) {
  return __uint_as_float(((unsigned int)s) << 16);
}

// ---------------------------------------------------------------- prep
// bid 0..127   : centroid hi/lo split + csq (8 rows/block, 32 lanes/row)
// bid 128..384 : zero dw+counts (257 blocks x 256 x float4 == 65792 float4)
// bid 385      : S = sum(ema_cs)
__global__ __launch_bounds__(256) void prep(const float* __restrict__ cent,
                                            const float* __restrict__ ema_cs,
                                            unsigned short* __restrict__ chp,
                                            unsigned short* __restrict__ clp,
                                            float* __restrict__ csq,
                                            float* __restrict__ dwzero,
                                            float* __restrict__ S) {
  const int bid = blockIdx.x;
  const int t   = threadIdx.x;
  if (bid < 128) {
    const int i = bid * 256 + t;                 // 8-elem unit; 32768 total
    const float4 a = ((const float4*)cent)[2 * i];
    const float4 b = ((const float4*)cent)[2 * i + 1];
    float f[8] = {a.x, a.y, a.z, a.w, b.x, b.y, b.z, b.w};
    union { unsigned short u[8]; uint4 v; } H, L;
    float ss = 0.f;
#pragma unroll
    for (int j = 0; j < 8; ++j) {
      H.u[j] = f2bf(f[j]);
      L.u[j] = f2bf(f[j] - bf2f(H.u[j]));
      ss += f[j] * f[j];
    }
    ((uint4*)chp)[i] = H.v;
    ((uint4*)clp)[i] = L.v;
#pragma unroll
    for (int off = 16; off; off >>= 1) ss += __shfl_down(ss, off, 32);
    if ((t & 31) == 0) csq[bid * 8 + (t >> 5)] = ss;   // row = i*8/256
  } else if (bid < 385) {
    const int i = (bid - 128) * 256 + t;
    ((float4*)dwzero)[i] = (float4){0.f, 0.f, 0.f, 0.f};
  } else {
    float s = ema_cs[t] + ema_cs[t + 256] + ema_cs[t + 512] + ema_cs[t + 768];
#pragma unroll
    for (int off = 32; off; off >>= 1) s += __shfl_down(s, off);
    __shared__ float wsum[4];
    if ((t & 63) == 0) wsum[t >> 6] = s;
    __syncthreads();
    if (t == 0) S[0] = wsum[0] + wsum[1] + wsum[2] + wsum[3];
  }
}

// ---------------------------------------------------------------- z hi/lo split
__global__ __launch_bounds__(256) void convert_hilo(const float* __restrict__ src,
                                                    unsigned short* __restrict__ hi,
                                                    unsigned short* __restrict__ lo,
                                                    int total8) {
  const int i = blockIdx.x * 256 + threadIdx.x;
  if (i >= total8) return;
  const float4 a = ((const float4*)src)[2 * i];
  const float4 b = ((const float4*)src)[2 * i + 1];
  float f[8] = {a.x, a.y, a.z, a.w, b.x, b.y, b.z, b.w};
  union { unsigned short u[8]; uint4 v; } H, L;
#pragma unroll
  for (int j = 0; j < 8; ++j) {
    H.u[j] = f2bf(f[j]);
    L.u[j] = f2bf(f[j] - bf2f(H.u[j]));
  }
  ((uint4*)hi)[i] = H.v;
  ((uint4*)lo)[i] = L.v;
}

// ---------------------------------------------------------------- MFMA dist GEMM
__global__ __launch_bounds__(256, 2) void dist_gemm_mfma(
    const unsigned short* __restrict__ zh, const unsigned short* __restrict__ zl,
    const unsigned short* __restrict__ ch, const unsigned short* __restrict__ cl,
    const float* __restrict__ csq, float* __restrict__ dist) {
  __shared__ unsigned short lds[4][128 * 64];  // Ah Al Bh Bl, 16 KB each

  const int tid  = threadIdx.x;
  const int lane = tid & 63;
  const int w    = tid >> 6;

  const int bid = blockIdx.x;
  const int lin = (bid & 7) * 128 + (bid >> 3);  // XCD-bijective (1024 % 8 == 0)
  const int m0  = (lin >> 3) * 128;
  const int n0  = (lin & 7) * 128;

  const int wm0 = (w >> 1) * 64;
  const int wn0 = (w & 1) * 64;

  f32x4 acc[4][4];
#pragma unroll
  for (int i = 0; i < 4; ++i)
#pragma unroll
    for (int j = 0; j < 4; ++j) acc[i][j] = (f32x4){0.f, 0.f, 0.f, 0.f};

  const int srow = lane >> 3;
  const int scb  = lane & 7;

  for (int d0 = 0; d0 < 256; d0 += 64) {
    __syncthreads();
#pragma unroll
    for (int j = 0; j < 4; ++j) {
      const int r0    = w * 32 + j * 8;
      const int row   = r0 + srow;
      const int chunk = scb ^ (row & 7);
      const size_t go = (size_t)(d0 + chunk * 8);
      gload16(zh + (size_t)(m0 + row) * 256 + go, &lds[0][r0 * 64]);
      gload16(zl + (size_t)(m0 + row) * 256 + go, &lds[1][r0 * 64]);
      gload16(ch + (size_t)(n0 + row) * 256 + go, &lds[2][r0 * 64]);
      gload16(cl + (size_t)(n0 + row) * 256 + go, &lds[3][r0 * 64]);
    }
    __syncthreads();
#pragma unroll
    for (int s = 0; s < 2; ++s) {
      bf16x8 ah[4], al[4], bh[4], bl[4];
      const int kg = s * 4 + (lane >> 4);
#pragma unroll
      for (int f = 0; f < 4; ++f) {
        const int ra = wm0 + f * 16 + (lane & 15);
        const int ca = kg ^ (ra & 7);
        ah[f] = *(const bf16x8*)&lds[0][ra * 64 + ca * 8];
        al[f] = *(const bf16x8*)&lds[1][ra * 64 + ca * 8];
        const int rb = wn0 + f * 16 + (lane & 15);
        const int cb = kg ^ (rb & 7);
        bh[f] = *(const bf16x8*)&lds[2][rb * 64 + cb * 8];
        bl[f] = *(const bf16x8*)&lds[3][rb * 64 + cb * 8];
      }
#pragma unroll
      for (int fm = 0; fm < 4; ++fm)
#pragma unroll
        for (int fn = 0; fn < 4; ++fn) {
          acc[fm][fn] = __builtin_amdgcn_mfma_f32_16x16x32_bf16(ah[fm], bh[fn], acc[fm][fn], 0, 0, 0);
          acc[fm][fn] = __builtin_amdgcn_mfma_f32_16x16x32_bf16(ah[fm], bl[fn], acc[fm][fn], 0, 0, 0);
          acc[fm][fn] = __builtin_amdgcn_mfma_f32_16x16x32_bf16(al[fm], bh[fn], acc[fm][fn], 0, 0, 0);
        }
    }
  }

#pragma unroll
  for (int fn = 0; fn < 4; ++fn) {
    const int col = n0 + wn0 + fn * 16 + (lane & 15);
    const float cq = csq[col];
#pragma unroll
    for (int fm = 0; fm < 4; ++fm) {
      const int row = m0 + wm0 + fm * 16 + ((lane >> 4) << 2);
#pragma unroll
      for (int r = 0; r < 4; ++r)
        dist[(size_t)(row + r) * 1024 + col] = cq - 2.0f * acc[fm][fn][r];
    }
  }
}

// ---------------------------------------------------------------- wave-per-row softmax + scatter
// 4 waves/block, 1 row each; 16 cols/lane; no LDS, no barriers.
__global__ __launch_bounds__(256) void row_softmax(const float* __restrict__ z,
                                                   const float* __restrict__ cent,
                                                   float* __restrict__ gamma,
                                                   float* __restrict__ recons,
                                                   float* __restrict__ dw,
                                                   float* __restrict__ counts) {
  const int wave = threadIdx.x >> 6;
  const int lane = threadIdx.x & 63;
  const int n = blockIdx.x * 4 + wave;
  float* row = gamma + (size_t)n * 1024;

  float4 s4[4];
  float mv = 3.0e38f; int mi = 0;
#pragma unroll
  for (int i = 0; i < 4; ++i) {
    s4[i] = *(const float4*)&row[i * 256 + lane * 4];
    const float* f = (const float*)&s4[i];
#pragma unroll
    for (int j = 0; j < 4; ++j) {
      if (f[j] < mv) { mv = f[j]; mi = i * 256 + lane * 4 + j; }
    }
  }
#pragma unroll
  for (int off = 32; off; off >>= 1) {
    const float ov = __shfl_down(mv, off);
    const int   oi = __shfl_down(mi, off);
    if (ov < mv || (ov == mv && oi < mi)) { mv = ov; mi = oi; }
  }
  mv = __shfl(mv, 0);
  mi = __shfl(mi, 0);

  float4 e4[4];
  float ls = 0.f;
#pragma unroll
  for (int i = 0; i < 4; ++i) {
    const float* f = (const float*)&s4[i];
    float* e = (float*)&e4[i];
#pragma unroll
    for (int j = 0; j < 4; ++j) {
      e[j] = __expf(-5.0f * (f[j] - mv));
      ls += e[j];
    }
  }
#pragma unroll
  for (int off = 32; off; off >>= 1) ls += __shfl_xor(ls, off);
  const float inv = 1.0f / ls;

#pragma unroll
  for (int i = 0; i < 4; ++i) {
    float4 g = e4[i];
    g.x *= inv; g.y *= inv; g.z *= inv; g.w *= inv;
    *(float4*)&row[i * 256 + lane * 4] = g;
  }

  const int idx = mi;
  const float4 zv = *(const float4*)&z[(size_t)n * 256 + lane * 4];
  const float4 cv = *(const float4*)&cent[(size_t)idx * 256 + lane * 4];
  *(float4*)&recons[(size_t)n * 256 + lane * 4] = cv;
  float* dp = &dw[(size_t)idx * 256 + lane * 4];
  atomicAdd(dp + 0, zv.x);
  atomicAdd(dp + 1, zv.y);
  atomicAdd(dp + 2, zv.z);
  atomicAdd(dp + 3, zv.w);
  if (lane == 0) atomicAdd(&counts[idx], 1.0f);
}

// ---------------------------------------------------------------- finalize
__global__ __launch_bounds__(256) void finalize(const float* __restrict__ ema_w,
                                                const float* __restrict__ ema_cs,
                                                const float* __restrict__ counts,
                                                const float* __restrict__ dw,
                                                const float* __restrict__ S,
                                                float* __restrict__ outc,
                                                float fN) {
  const int k = blockIdx.x;
  const int t = threadIdx.x;
  const float n   = DECAY * S[0] + OMD * fN;        // sum(new_cs): sum(counts)==N
  const float v   = DECAY * ema_cs[k] + OMD * counts[k];
  const float ncs = (v + EPSV) / (n + 1024.0f * EPSV) * n;
  const size_t i  = (size_t)k * 256 + t;
  outc[i] = (DECAY * ema_w[i] + OMD * dw[i]) / ncs;
}

// ---------------------------------------------------------------- launch
extern "C" void kernel_launch(void* const* d_in, const int* in_sizes, int n_in,
                              void* d_out, int out_size, void* d_ws, size_t ws_size,
                              hipStream_t stream) {
  const float* z      = (const float*)d_in[0];
  const float* cent   = (const float*)d_in[1];
  const float* ema_w  = (const float*)d_in[2];
  const float* ema_cs = (const float*)d_in[3];

  const int K = in_sizes[3];            // 1024
  const int D = in_sizes[1] / K;        // 256
  const int N = in_sizes[0] / D;        // 16384

  float* out    = (float*)d_out;
  float* recons = out;                              // [N,D]
  float* gamma  = out + (size_t)N * D;              // [N,K] (dist, then gamma)
  float* outc   = gamma + (size_t)N * K;            // [K,D]

  unsigned short* zh  = (unsigned short*)recons;    // N*D shorts
  unsigned short* zl  = zh + (size_t)N * D;         // N*D shorts (fills recons exactly)
  unsigned short* chp = (unsigned short*)outc;      // K*D shorts
  unsigned short* clp = chp + (size_t)K * D;        // K*D shorts (fills outc exactly)

  float* dw     = (float*)d_ws;                     // [K,D]
  float* counts = dw + (size_t)K * D;               // [K]
  float* csq    = counts + K;                       // [K]
  float* S      = csq + K;                          // [1]

  prep<<<386, 256, 0, stream>>>(cent, ema_cs, chp, clp, csq, dw, S);

  convert_hilo<<<(N * D / 8 + 255) / 256, 256, 0, stream>>>(z, zh, zl, N * D / 8);

  dist_gemm_mfma<<<(N / 128) * (K / 128), 256, 0, stream>>>(zh, zl, chp, clp, csq, gamma);

  row_softmax<<<N / 4, 256, 0, stream>>>(z, cent, gamma, recons, dw, counts);

  finalize<<<K, 256, 0, stream>>>(ema_w, ema_cs, counts, dw, S, outc, (float)N);
}

// Round 6
// 84.107 us; speedup vs baseline: 2.1393x; 2.1393x over previous
//
#include <hip/hip_runtime.h>
#include <hip/hip_bf16.h>

// VectorQuantizerEMA: N=16384, K=1024, D=256.
// Outputs (f32, concat): recons [N,D] | gamma [N,K] | new_centroids [K,D]
// R6: revert softmax to R4 block-per-row (R5's wave-per-row was latency-bound,
// 133us). Keep consolidation: prep fuses z-convert + cent-convert + csq +
// ws-zero + sum(ema_cs); finalize computes newcs analytically. 4 kernels.

#define DECAY 0.95f
#define OMD   0.05f
#define EPSV  1e-5f

using f32x4  = __attribute__((ext_vector_type(4))) float;
using bf16x8 = __attribute__((ext_vector_type(8))) __bf16;

typedef __attribute__((address_space(3))) unsigned int       lds_uint;
typedef const __attribute__((address_space(1))) unsigned int glb_uint;

__device__ __forceinline__ void gload16(const void* g, const void* l) {
  __builtin_amdgcn_global_load_lds((glb_uint*)(unsigned long long)g,
                                   (lds_uint*)(unsigned int)(unsigned long long)l,
                                   16, 0, 0);
}

__device__ __forceinline__ unsigned short f2bf(float f) {
  unsigned int u = __float_as_uint(f);
  unsigned int r = (u + 0x7FFFu + ((u >> 16) & 1u)) >> 16;
  return (unsigned short)r;
}
__device__ __forceinline__ float bf2f(unsigned short s) {
  return __uint_as_float(((unsigned int)s) << 16);
}

// ---------------------------------------------------------------- prep
// bid 0..2047    : z hi/lo split (8 floats per thread)
// bid 2048..2175 : centroid hi/lo split + csq (8 rows/block, 32 lanes/row)
// bid 2176..2432 : zero dw+counts (257 x 256 x float4 = 263168 floats >= 263168)
// bid 2433       : S = sum(ema_cs)
__global__ __launch_bounds__(256) void prep(const float* __restrict__ z,
                                            const float* __restrict__ cent,
                                            const float* __restrict__ ema_cs,
                                            unsigned short* __restrict__ zh,
                                            unsigned short* __restrict__ zl,
                                            unsigned short* __restrict__ chp,
                                            unsigned short* __restrict__ clp,
                                            float* __restrict__ csq,
                                            float* __restrict__ dwzero,
                                            float* __restrict__ S) {
  const int bid = blockIdx.x;
  const int t   = threadIdx.x;
  if (bid < 2048) {
    const int i = bid * 256 + t;                 // 8-elem units over z
    const float4 a = ((const float4*)z)[2 * i];
    const float4 b = ((const float4*)z)[2 * i + 1];
    float f[8] = {a.x, a.y, a.z, a.w, b.x, b.y, b.z, b.w};
    union { unsigned short u[8]; uint4 v; } H, L;
#pragma unroll
    for (int j = 0; j < 8; ++j) {
      H.u[j] = f2bf(f[j]);
      L.u[j] = f2bf(f[j] - bf2f(H.u[j]));
    }
    ((uint4*)zh)[i] = H.v;
    ((uint4*)zl)[i] = L.v;
  } else if (bid < 2176) {
    const int i = (bid - 2048) * 256 + t;        // 8-elem units over cent
    const float4 a = ((const float4*)cent)[2 * i];
    const float4 b = ((const float4*)cent)[2 * i + 1];
    float f[8] = {a.x, a.y, a.z, a.w, b.x, b.y, b.z, b.w};
    union { unsigned short u[8]; uint4 v; } H, L;
    float ss = 0.f;
#pragma unroll
    for (int j = 0; j < 8; ++j) {
      H.u[j] = f2bf(f[j]);
      L.u[j] = f2bf(f[j] - bf2f(H.u[j]));
      ss += f[j] * f[j];
    }
    ((uint4*)chp)[i] = H.v;
    ((uint4*)clp)[i] = L.v;
#pragma unroll
    for (int off = 16; off; off >>= 1) ss += __shfl_down(ss, off, 32);
    if ((t & 31) == 0) csq[(bid - 2048) * 8 + (t >> 5)] = ss;
  } else if (bid < 2433) {
    const int i = (bid - 2176) * 256 + t;
    ((float4*)dwzero)[i] = (float4){0.f, 0.f, 0.f, 0.f};
  } else {
    float s = ema_cs[t] + ema_cs[t + 256] + ema_cs[t + 512] + ema_cs[t + 768];
#pragma unroll
    for (int off = 32; off; off >>= 1) s += __shfl_down(s, off);
    __shared__ float wsum[4];
    if ((t & 63) == 0) wsum[t >> 6] = s;
    __syncthreads();
    if (t == 0) S[0] = wsum[0] + wsum[1] + wsum[2] + wsum[3];
  }
}

// ---------------------------------------------------------------- MFMA dist GEMM
__global__ __launch_bounds__(256, 2) void dist_gemm_mfma(
    const unsigned short* __restrict__ zh, const unsigned short* __restrict__ zl,
    const unsigned short* __restrict__ ch, const unsigned short* __restrict__ cl,
    const float* __restrict__ csq, float* __restrict__ dist) {
  __shared__ unsigned short lds[4][128 * 64];  // Ah Al Bh Bl, 16 KB each

  const int tid  = threadIdx.x;
  const int lane = tid & 63;
  const int w    = tid >> 6;

  const int bid = blockIdx.x;
  const int lin = (bid & 7) * 128 + (bid >> 3);  // XCD-bijective (1024 % 8 == 0)
  const int m0  = (lin >> 3) * 128;
  const int n0  = (lin & 7) * 128;

  const int wm0 = (w >> 1) * 64;
  const int wn0 = (w & 1) * 64;

  f32x4 acc[4][4];
#pragma unroll
  for (int i = 0; i < 4; ++i)
#pragma unroll
    for (int j = 0; j < 4; ++j) acc[i][j] = (f32x4){0.f, 0.f, 0.f, 0.f};

  const int srow = lane >> 3;
  const int scb  = lane & 7;

  for (int d0 = 0; d0 < 256; d0 += 64) {
    __syncthreads();
#pragma unroll
    for (int j = 0; j < 4; ++j) {
      const int r0    = w * 32 + j * 8;
      const int row   = r0 + srow;
      const int chunk = scb ^ (row & 7);
      const size_t go = (size_t)(d0 + chunk * 8);
      gload16(zh + (size_t)(m0 + row) * 256 + go, &lds[0][r0 * 64]);
      gload16(zl + (size_t)(m0 + row) * 256 + go, &lds[1][r0 * 64]);
      gload16(ch + (size_t)(n0 + row) * 256 + go, &lds[2][r0 * 64]);
      gload16(cl + (size_t)(n0 + row) * 256 + go, &lds[3][r0 * 64]);
    }
    __syncthreads();
#pragma unroll
    for (int s = 0; s < 2; ++s) {
      bf16x8 ah[4], al[4], bh[4], bl[4];
      const int kg = s * 4 + (lane >> 4);
#pragma unroll
      for (int f = 0; f < 4; ++f) {
        const int ra = wm0 + f * 16 + (lane & 15);
        const int ca = kg ^ (ra & 7);
        ah[f] = *(const bf16x8*)&lds[0][ra * 64 + ca * 8];
        al[f] = *(const bf16x8*)&lds[1][ra * 64 + ca * 8];
        const int rb = wn0 + f * 16 + (lane & 15);
        const int cb = kg ^ (rb & 7);
        bh[f] = *(const bf16x8*)&lds[2][rb * 64 + cb * 8];
        bl[f] = *(const bf16x8*)&lds[3][rb * 64 + cb * 8];
      }
#pragma unroll
      for (int fm = 0; fm < 4; ++fm)
#pragma unroll
        for (int fn = 0; fn < 4; ++fn) {
          acc[fm][fn] = __builtin_amdgcn_mfma_f32_16x16x32_bf16(ah[fm], bh[fn], acc[fm][fn], 0, 0, 0);
          acc[fm][fn] = __builtin_amdgcn_mfma_f32_16x16x32_bf16(ah[fm], bl[fn], acc[fm][fn], 0, 0, 0);
          acc[fm][fn] = __builtin_amdgcn_mfma_f32_16x16x32_bf16(al[fm], bh[fn], acc[fm][fn], 0, 0, 0);
        }
    }
  }

#pragma unroll
  for (int fn = 0; fn < 4; ++fn) {
    const int col = n0 + wn0 + fn * 16 + (lane & 15);
    const float cq = csq[col];
#pragma unroll
    for (int fm = 0; fm < 4; ++fm) {
      const int row = m0 + wm0 + fm * 16 + ((lane >> 4) << 2);
#pragma unroll
      for (int r = 0; r < 4; ++r)
        dist[(size_t)(row + r) * 1024 + col] = cq - 2.0f * acc[fm][fn][r];
    }
  }
}

// ---------------------------------------------------------------- row softmax + scatter
// R4 structure: block-per-row, 256 threads, float4 each. In-place dist->gamma.
__global__ __launch_bounds__(256) void row_softmax(const float* __restrict__ z,
                                                   const float* __restrict__ cent,
                                                   float* __restrict__ gamma,
                                                   float* __restrict__ recons,
                                                   float* __restrict__ dw,
                                                   float* __restrict__ counts,
                                                   int K) {
  const int n = blockIdx.x;
  const int t = threadIdx.x;
  float* row = gamma + (size_t)n * K;
  const float4 s = ((const float4*)row)[t];

  float mv = s.x; int mi = 4 * t;
  if (s.y < mv) { mv = s.y; mi = 4 * t + 1; }
  if (s.z < mv) { mv = s.z; mi = 4 * t + 2; }
  if (s.w < mv) { mv = s.w; mi = 4 * t + 3; }

#pragma unroll
  for (int off = 32; off; off >>= 1) {
    const float ov = __shfl_down(mv, off);
    const int   oi = __shfl_down(mi, off);
    if (ov < mv || (ov == mv && oi < mi)) { mv = ov; mi = oi; }
  }

  __shared__ float wv[4];
  __shared__ int   wi[4];
  __shared__ float fmin_s;
  __shared__ int   fidx_s;
  __shared__ float fsum_s;
  const int wave = t >> 6;
  if ((t & 63) == 0) { wv[wave] = mv; wi[wave] = mi; }
  __syncthreads();
  if (t == 0) {
    float bv = wv[0]; int bi = wi[0];
#pragma unroll
    for (int wq = 1; wq < 4; ++wq)
      if (wv[wq] < bv || (wv[wq] == bv && wi[wq] < bi)) { bv = wv[wq]; bi = wi[wq]; }
    fmin_s = bv; fidx_s = bi;
  }
  __syncthreads();

  const float bm = fmin_s;
  const float e0 = __expf(-5.0f * (s.x - bm));
  const float e1 = __expf(-5.0f * (s.y - bm));
  const float e2 = __expf(-5.0f * (s.z - bm));
  const float e3 = __expf(-5.0f * (s.w - bm));
  float ls = e0 + e1 + e2 + e3;
#pragma unroll
  for (int off = 32; off; off >>= 1) ls += __shfl_down(ls, off);
  if ((t & 63) == 0) wv[wave] = ls;
  __syncthreads();
  if (t == 0) fsum_s = wv[0] + wv[1] + wv[2] + wv[3];
  __syncthreads();

  const float inv = 1.0f / fsum_s;
  float4 g;
  g.x = e0 * inv; g.y = e1 * inv; g.z = e2 * inv; g.w = e3 * inv;
  ((float4*)row)[t] = g;

  const int idx = fidx_s;
  const float zv = z[(size_t)n * 256 + t];
  recons[(size_t)n * 256 + t] = cent[(size_t)idx * 256 + t];
  atomicAdd(&dw[(size_t)idx * 256 + t], zv);
  if (t == 0) atomicAdd(&counts[idx], 1.0f);
}

// ---------------------------------------------------------------- finalize
__global__ __launch_bounds__(256) void finalize(const float* __restrict__ ema_w,
                                                const float* __restrict__ ema_cs,
                                                const float* __restrict__ counts,
                                                const float* __restrict__ dw,
                                                const float* __restrict__ S,
                                                float* __restrict__ outc,
                                                float fN) {
  const int k = blockIdx.x;
  const int t = threadIdx.x;
  const float n   = DECAY * S[0] + OMD * fN;        // sum(new_cs): sum(counts)==N
  const float v   = DECAY * ema_cs[k] + OMD * counts[k];
  const float ncs = (v + EPSV) / (n + 1024.0f * EPSV) * n;
  const size_t i  = (size_t)k * 256 + t;
  outc[i] = (DECAY * ema_w[i] + OMD * dw[i]) / ncs;
}

// ---------------------------------------------------------------- launch
extern "C" void kernel_launch(void* const* d_in, const int* in_sizes, int n_in,
                              void* d_out, int out_size, void* d_ws, size_t ws_size,
                              hipStream_t stream) {
  const float* z      = (const float*)d_in[0];
  const float* cent   = (const float*)d_in[1];
  const float* ema_w  = (const float*)d_in[2];
  const float* ema_cs = (const float*)d_in[3];

  const int K = in_sizes[3];            // 1024
  const int D = in_sizes[1] / K;        // 256
  const int N = in_sizes[0] / D;        // 16384

  float* out    = (float*)d_out;
  float* recons = out;                              // [N,D]
  float* gamma  = out + (size_t)N * D;              // [N,K] (dist, then gamma)
  float* outc   = gamma + (size_t)N * K;            // [K,D]

  unsigned short* zh  = (unsigned short*)recons;    // N*D shorts
  unsigned short* zl  = zh + (size_t)N * D;         // N*D shorts (fills recons exactly)
  unsigned short* chp = (unsigned short*)outc;      // K*D shorts
  unsigned short* clp = chp + (size_t)K * D;        // K*D shorts (fills outc exactly)

  float* dw     = (float*)d_ws;                     // [K,D]
  float* counts = dw + (size_t)K * D;               // [K]
  float* csq    = counts + K;                       // [K]
  float* S      = csq + K;                          // [1]

  prep<<<2434, 256, 0, stream>>>(z, cent, ema_cs, zh, zl, chp, clp, csq, dw, S);

  dist_gemm_mfma<<<(N / 128) * (K / 128), 256, 0, stream>>>(zh, zl, chp, clp, csq, gamma);

  row_softmax<<<N, 256, 0, stream>>>(z, cent, gamma, recons, dw, counts, K);

  finalize<<<K, 256, 0, stream>>>(ema_w, ema_cs, counts, dw, S, outc, (float)N);
}

// Round 7
// 77.674 us; speedup vs baseline: 2.3165x; 1.0828x over previous
//
#include <hip/hip_runtime.h>

// VectorQuantizerEMA: N=16384, K=1024, D=256.
// Outputs (f32, concat): recons [N,D] | gamma [N,K] | new_centroids [K,D]
// R7: int8 3-term distance GEMM. z = sz*(h + l/256), c = sc*(h + l/256);
// dot = sz*sc*(acc_hh + acc_hl_lh/256) via 3x mfma_i32_32x32x32_i8 (2 acc).
// Packed staging: [row][kstep][64B h | 64B l], gload16 + XOR chunk swizzle.

#define DECAY 0.95f
#define OMD   0.05f
#define EPSV  1e-5f

using i32x4  = __attribute__((ext_vector_type(4))) int;
using i32x16 = __attribute__((ext_vector_type(16))) int;

typedef __attribute__((address_space(3))) unsigned int       lds_uint;
typedef const __attribute__((address_space(1))) unsigned int glb_uint;

__device__ __forceinline__ void gload16(const void* g, const void* l) {
  __builtin_amdgcn_global_load_lds((glb_uint*)(unsigned long long)g,
                                   (lds_uint*)(unsigned int)(unsigned long long)l,
                                   16, 0, 0);
}

// ---------------------------------------------------------------- prep
// bid 0..2047    : z int8 hi/lo quantize (8 rows/block) + sz
// bid 2048..2175 : cent int8 quantize + sc + csq
// bid 2176..2432 : zero dw+counts
// bid 2433       : S = sum(ema_cs)
__global__ __launch_bounds__(256) void prep(const float* __restrict__ z,
                                            const float* __restrict__ cent,
                                            const float* __restrict__ ema_cs,
                                            signed char* __restrict__ z8,
                                            signed char* __restrict__ c8,
                                            float* __restrict__ sz,
                                            float* __restrict__ sc,
                                            float* __restrict__ csq,
                                            float* __restrict__ dwzero,
                                            float* __restrict__ S) {
  const int bid = blockIdx.x;
  const int t   = threadIdx.x;
  if (bid < 2176) {
    const bool isz = bid < 2048;
    const float* src = isz ? z : cent;
    const int rb = isz ? bid : (bid - 2048);
    const int r  = rb * 8 + (t >> 5);            // global row
    const int d0 = (t & 31) * 8;                 // 32 lanes x 8 elems = 256
    const float4 a = *(const float4*)&src[(size_t)r * 256 + d0];
    const float4 b = *(const float4*)&src[(size_t)r * 256 + d0 + 4];
    float f[8] = {a.x, a.y, a.z, a.w, b.x, b.y, b.z, b.w};
    float am = 0.f, ssq = 0.f;
#pragma unroll
    for (int j = 0; j < 8; ++j) { am = fmaxf(am, fabsf(f[j])); ssq += f[j] * f[j]; }
#pragma unroll
    for (int off = 16; off; off >>= 1) {
      am  = fmaxf(am, __shfl_down(am, off, 32));
      ssq += __shfl_down(ssq, off, 32);
    }
    am = __shfl(am, 0, 32);                      // broadcast row max
    const float s  = fmaxf(am, 1e-6f) * (1.0f / 127.0f);
    const float rs = 1.0f / s;
    union { signed char c[8]; uint2 u; } H, L;
#pragma unroll
    for (int j = 0; j < 8; ++j) {
      float q = rintf(f[j] * rs);
      q = fminf(fmaxf(q, -127.f), 127.f);
      H.c[j] = (signed char)(int)q;
      float res = f[j] - q * s;
      float lq = rintf(res * rs * 256.0f);
      lq = fminf(fmaxf(lq, -127.f), 127.f);
      L.c[j] = (signed char)(int)lq;
    }
    signed char* dst = (isz ? z8 : c8) + (size_t)r * 512 + (d0 >> 6) * 128 + (d0 & 63);
    *(uint2*)dst        = H.u;
    *(uint2*)(dst + 64) = L.u;
    if ((t & 31) == 0) {
      if (isz) sz[r] = s;
      else { sc[r] = s; csq[r] = ssq; }
    }
  } else if (bid < 2433) {
    const int i = (bid - 2176) * 256 + t;
    ((float4*)dwzero)[i] = (float4){0.f, 0.f, 0.f, 0.f};
  } else {
    float s = ema_cs[t] + ema_cs[t + 256] + ema_cs[t + 512] + ema_cs[t + 768];
#pragma unroll
    for (int off = 32; off; off >>= 1) s += __shfl_down(s, off);
    __shared__ float wsum[4];
    if ((t & 63) == 0) wsum[t >> 6] = s;
    __syncthreads();
    if (t == 0) S[0] = wsum[0] + wsum[1] + wsum[2] + wsum[3];
  }
}

// ---------------------------------------------------------------- i8 dist GEMM
// 128x128 tile, 4 waves 2x2 (64x64 quadrant = 2x2 frags of 32x32), BK=64.
__global__ __launch_bounds__(256, 2) void dist_gemm_i8(
    const signed char* __restrict__ z8, const signed char* __restrict__ c8,
    const float* __restrict__ sz, const float* __restrict__ sc,
    const float* __restrict__ csq, float* __restrict__ dist) {
  __shared__ signed char lds[2][128 * 128];   // [A|B][row][64 h | 64 l] = 32 KB

  const int tid  = threadIdx.x;
  const int lane = tid & 63;
  const int w    = tid >> 6;

  const int bid = blockIdx.x;
  const int lin = (bid & 7) * 128 + (bid >> 3);   // XCD-bijective (1024 % 8 == 0)
  const int m0  = (lin >> 3) * 128;
  const int n0  = (lin & 7) * 128;

  const int wm0 = (w >> 1) * 64;
  const int wn0 = (w & 1) * 64;

  i32x16 accA[2][2];   // hh
  i32x16 accB[2][2];   // h*l + l*h  (both scaled 1/256)
#pragma unroll
  for (int i = 0; i < 2; ++i)
#pragma unroll
    for (int j = 0; j < 2; ++j) {
      accA[i][j] = (i32x16)(0);
      accB[i][j] = (i32x16)(0);
    }

  const int srow = lane >> 3;     // 8 rows per gload16 (128B/row)
  const int scb  = lane & 7;

  for (int kk = 0; kk < 4; ++kk) {
    __syncthreads();
#pragma unroll
    for (int j = 0; j < 4; ++j) {
      const int r0    = w * 32 + j * 8;
      const int row   = r0 + srow;
      const int chunk = scb ^ (row & 7);
      gload16(z8 + (size_t)(m0 + row) * 512 + kk * 128 + chunk * 16, &lds[0][r0 * 128]);
      gload16(c8 + (size_t)(n0 + row) * 512 + kk * 128 + chunk * 16, &lds[1][r0 * 128]);
    }
    __syncthreads();
#pragma unroll
    for (int s = 0; s < 2; ++s) {
      i32x4 ah[2], al[2], bh[2], bl[2];
      const int kc = s * 2 + (lane >> 5);        // h chunk 0..3; l = +4
#pragma unroll
      for (int fi = 0; fi < 2; ++fi) {
        const int ra = wm0 + fi * 32 + (lane & 31);
        ah[fi] = *(const i32x4*)&lds[0][ra * 128 + ((kc)     ^ (ra & 7)) * 16];
        al[fi] = *(const i32x4*)&lds[0][ra * 128 + ((kc + 4) ^ (ra & 7)) * 16];
        const int rb = wn0 + fi * 32 + (lane & 31);
        bh[fi] = *(const i32x4*)&lds[1][rb * 128 + ((kc)     ^ (rb & 7)) * 16];
        bl[fi] = *(const i32x4*)&lds[1][rb * 128 + ((kc + 4) ^ (rb & 7)) * 16];
      }
#pragma unroll
      for (int i = 0; i < 2; ++i)
#pragma unroll
        for (int j = 0; j < 2; ++j) {
          accA[i][j] = __builtin_amdgcn_mfma_i32_32x32x32_i8(ah[i], bh[j], accA[i][j], 0, 0, 0);
          accB[i][j] = __builtin_amdgcn_mfma_i32_32x32x32_i8(ah[i], bl[j], accB[i][j], 0, 0, 0);
          accB[i][j] = __builtin_amdgcn_mfma_i32_32x32x32_i8(al[i], bh[j], accB[i][j], 0, 0, 0);
        }
    }
  }

#pragma unroll
  for (int j = 0; j < 2; ++j) {
    const int colb = n0 + wn0 + j * 32 + (lane & 31);
    const float scv = sc[colb];
    const float cqv = csq[colb];
#pragma unroll
    for (int i = 0; i < 2; ++i) {
#pragma unroll
      for (int reg = 0; reg < 16; ++reg) {
        const int row = m0 + wm0 + i * 32 + (reg & 3) + 8 * (reg >> 2) + 4 * (lane >> 5);
        const float dotv = (float)accA[i][j][reg] + (float)accB[i][j][reg] * (1.0f / 256.0f);
        dist[(size_t)row * 1024 + colb] = cqv - 2.0f * sz[row] * scv * dotv;
      }
    }
  }
}

// ---------------------------------------------------------------- row softmax + scatter
__global__ __launch_bounds__(256) void row_softmax(const float* __restrict__ z,
                                                   const float* __restrict__ cent,
                                                   float* __restrict__ gamma,
                                                   float* __restrict__ recons,
                                                   float* __restrict__ dw,
                                                   float* __restrict__ counts,
                                                   int K) {
  const int n = blockIdx.x;
  const int t = threadIdx.x;
  float* row = gamma + (size_t)n * K;
  const float4 s = ((const float4*)row)[t];

  float mv = s.x; int mi = 4 * t;
  if (s.y < mv) { mv = s.y; mi = 4 * t + 1; }
  if (s.z < mv) { mv = s.z; mi = 4 * t + 2; }
  if (s.w < mv) { mv = s.w; mi = 4 * t + 3; }

#pragma unroll
  for (int off = 32; off; off >>= 1) {
    const float ov = __shfl_down(mv, off);
    const int   oi = __shfl_down(mi, off);
    if (ov < mv || (ov == mv && oi < mi)) { mv = ov; mi = oi; }
  }

  __shared__ float wv[4];
  __shared__ int   wi[4];
  __shared__ float fmin_s;
  __shared__ int   fidx_s;
  __shared__ float fsum_s;
  const int wave = t >> 6;
  if ((t & 63) == 0) { wv[wave] = mv; wi[wave] = mi; }
  __syncthreads();
  if (t == 0) {
    float bv = wv[0]; int bi = wi[0];
#pragma unroll
    for (int wq = 1; wq < 4; ++wq)
      if (wv[wq] < bv || (wv[wq] == bv && wi[wq] < bi)) { bv = wv[wq]; bi = wi[wq]; }
    fmin_s = bv; fidx_s = bi;
  }
  __syncthreads();

  const float bm = fmin_s;
  const float e0 = __expf(-5.0f * (s.x - bm));
  const float e1 = __expf(-5.0f * (s.y - bm));
  const float e2 = __expf(-5.0f * (s.z - bm));
  const float e3 = __expf(-5.0f * (s.w - bm));
  float ls = e0 + e1 + e2 + e3;
#pragma unroll
  for (int off = 32; off; off >>= 1) ls += __shfl_down(ls, off);
  if ((t & 63) == 0) wv[wave] = ls;
  __syncthreads();
  if (t == 0) fsum_s = wv[0] + wv[1] + wv[2] + wv[3];
  __syncthreads();

  const float inv = 1.0f / fsum_s;
  float4 g;
  g.x = e0 * inv; g.y = e1 * inv; g.z = e2 * inv; g.w = e3 * inv;
  ((float4*)row)[t] = g;

  const int idx = fidx_s;
  const float zv = z[(size_t)n * 256 + t];
  recons[(size_t)n * 256 + t] = cent[(size_t)idx * 256 + t];
  atomicAdd(&dw[(size_t)idx * 256 + t], zv);
  if (t == 0) atomicAdd(&counts[idx], 1.0f);
}

// ---------------------------------------------------------------- finalize
__global__ __launch_bounds__(256) void finalize(const float* __restrict__ ema_w,
                                                const float* __restrict__ ema_cs,
                                                const float* __restrict__ counts,
                                                const float* __restrict__ dw,
                                                const float* __restrict__ S,
                                                float* __restrict__ outc,
                                                float fN) {
  const int k = blockIdx.x;
  const int t = threadIdx.x;
  const float n   = DECAY * S[0] + OMD * fN;        // sum(new_cs): sum(counts)==N
  const float v   = DECAY * ema_cs[k] + OMD * counts[k];
  const float ncs = (v + EPSV) / (n + 1024.0f * EPSV) * n;
  const size_t i  = (size_t)k * 256 + t;
  outc[i] = (DECAY * ema_w[i] + OMD * dw[i]) / ncs;
}

// ---------------------------------------------------------------- launch
extern "C" void kernel_launch(void* const* d_in, const int* in_sizes, int n_in,
                              void* d_out, int out_size, void* d_ws, size_t ws_size,
                              hipStream_t stream) {
  const float* z      = (const float*)d_in[0];
  const float* cent   = (const float*)d_in[1];
  const float* ema_w  = (const float*)d_in[2];
  const float* ema_cs = (const float*)d_in[3];

  const int K = in_sizes[3];            // 1024
  const int D = in_sizes[1] / K;        // 256
  const int N = in_sizes[0] / D;        // 16384

  float* out    = (float*)d_out;
  float* recons = out;                              // [N,D]
  float* gamma  = out + (size_t)N * D;              // [N,K] (dist, then gamma)
  float* outc   = gamma + (size_t)N * K;            // [K,D]

  // scratch parked in output regions that are overwritten later:
  signed char* z8 = (signed char*)recons;           // N*512 B (8 MB <= 16 MB region)
  signed char* c8 = (signed char*)outc;             // K*512 B
  float* sz = outc + (size_t)K * 512 / 4;           // after c8: N floats
  float* sc = sz + N;                               // K floats (total 644 KB <= 1 MB)

  float* dw     = (float*)d_ws;                     // [K,D]
  float* counts = dw + (size_t)K * D;               // [K]
  float* csq    = counts + K;                       // [K]
  float* S      = csq + K;                          // [1]

  prep<<<2434, 256, 0, stream>>>(z, cent, ema_cs, z8, c8, sz, sc, csq, dw, S);

  dist_gemm_i8<<<(N / 128) * (K / 128), 256, 0, stream>>>(z8, c8, sz, sc, csq, gamma);

  row_softmax<<<N, 256, 0, stream>>>(z, cent, gamma, recons, dw, counts, K);

  finalize<<<K, 256, 0, stream>>>(ema_w, ema_cs, counts, dw, S, outc, (float)N);
}